// Round 10
// baseline (421.646 us; speedup 1.0000x reference)
//
#include <hip/hip_runtime.h>

typedef unsigned short u16;
typedef __bf16 bf16x8 __attribute__((ext_vector_type(8)));
typedef u16    u16x8  __attribute__((ext_vector_type(8)));
typedef float  f32x4  __attribute__((ext_vector_type(4)));

__device__ __forceinline__ u16 f2bf(float f) {
    union { float f; unsigned u; } x{f};
    unsigned r = x.u + 0x7fffu + ((x.u >> 16) & 1u);
    return (u16)(r >> 16);
}
__device__ __forceinline__ float bf2f(u16 h) {
    union { unsigned u; float f; } x{(unsigned)h << 16};
    return x.f;
}

__device__ __forceinline__ f32x4 mfma16(bf16x8 a, bf16x8 b, f32x4 c) {
    return __builtin_amdgcn_mfma_f32_16x16x32_bf16(a, b, c, 0, 0, 0);
}

// async global->LDS, 16B per lane; LDS dest is wave-uniform base + lane*16
__device__ __forceinline__ void async_ld16(const void* g, void* l) {
    __builtin_amdgcn_global_load_lds(
        (const __attribute__((address_space(1))) unsigned int*)g,
        (__attribute__((address_space(3))) unsigned int*)l, 16, 0, 0);
}

// ---------------- unified prep: weight transposes + bias concat + LN1/LN3, ONE dispatch -----
struct PrepParams {
    const float* src[8];
    u16* dst[8];
    int K[8], N[8];
    int pfx[9];
    const float *bq, *bk, *bv;
    float* bqkv;
    const float *x, *g1, *b1, *g3, *b3;
    u16 *o1, *o3;    // hbuf (ln1), nrm (ln3)
};

__global__ void prep_kernel(PrepParams p) {
    const int b = blockIdx.x;
    const int t = threadIdx.x;
    __shared__ float tile[64][65];
    __shared__ float red[8];

    if (b >= p.pfx[8] + 12) {   // LN1+LN3 tail (4096 blocks, one row each)
        const int row = b - p.pfx[8] - 12;
        const long base = (long)row * 1024;
        float4 v = ((const float4*)(p.x + base))[t];
        float s = v.x + v.y + v.z + v.w;
        float ss = v.x * v.x + v.y * v.y + v.z * v.z + v.w * v.w;
        for (int o = 32; o > 0; o >>= 1) { s += __shfl_down(s, o); ss += __shfl_down(ss, o); }
        if ((t & 63) == 0) { red[t >> 6] = s; red[(t >> 6) + 4] = ss; }
        __syncthreads();
        float sum = red[0] + red[1] + red[2] + red[3];
        float sq  = red[4] + red[5] + red[6] + red[7];
        const float mean = sum * (1.f / 1024.f);
        const float rstd = rsqrtf(sq * (1.f / 1024.f) - mean * mean + 1e-5f);
        float4 G1 = ((const float4*)p.g1)[t], B1 = ((const float4*)p.b1)[t];
        float4 G3 = ((const float4*)p.g3)[t], B3 = ((const float4*)p.b3)[t];
        float n0 = (v.x - mean) * rstd, n1 = (v.y - mean) * rstd;
        float n2 = (v.z - mean) * rstd, n3 = (v.w - mean) * rstd;
        ushort4 o1, o3;
        o1.x = f2bf(n0 * G1.x + B1.x); o1.y = f2bf(n1 * G1.y + B1.y);
        o1.z = f2bf(n2 * G1.z + B1.z); o1.w = f2bf(n3 * G1.w + B1.w);
        o3.x = f2bf(n0 * G3.x + B3.x); o3.y = f2bf(n1 * G3.y + B3.y);
        o3.z = f2bf(n2 * G3.z + B3.z); o3.w = f2bf(n3 * G3.w + B3.w);
        ((ushort4*)(p.o1 + base))[t] = o1;
        ((ushort4*)(p.o3 + base))[t] = o3;
        return;
    }
    if (b >= p.pfx[8]) {        // bias-concat tail
        int i = (b - p.pfx[8]) * 256 + t;
        p.bqkv[i] = i < 1024 ? p.bq[i] : (i < 2048 ? p.bk[i - 1024] : p.bv[i - 2048]);
        return;
    }
    int j = 0;
    while (b >= p.pfx[j + 1]) ++j;
    const float* __restrict__ in = p.src[j];
    u16* __restrict__ out = p.dst[j];
    const int K = p.K[j], N = p.N[j];
    const int local = b - p.pfx[j];
    const int tx = N >> 6;
    const int n0 = (local % tx) * 64, k0 = (local / tx) * 64;
    const int rr = t >> 4, cc = t & 15;
#pragma unroll
    for (int it = 0; it < 4; ++it) {
        const int r = rr + it * 16;
        float4 v = *(const float4*)(in + (long)(k0 + r) * N + n0 + cc * 4);
        tile[r][cc * 4 + 0] = v.x; tile[r][cc * 4 + 1] = v.y;
        tile[r][cc * 4 + 2] = v.z; tile[r][cc * 4 + 3] = v.w;
    }
    __syncthreads();
#pragma unroll
    for (int it = 0; it < 4; ++it) {
        const int n = rr + it * 16;
        ushort4 o;
        o.x = f2bf(tile[cc * 4 + 0][n]);
        o.y = f2bf(tile[cc * 4 + 1][n]);
        o.z = f2bf(tile[cc * 4 + 2][n]);
        o.w = f2bf(tile[cc * 4 + 3][n]);
        *(ushort4*)(out + (long)(n0 + n) * K + k0 + cc * 4) = o;
    }
}

// ---------------- V transpose: qkv[tok][2048+h*64+d] -> vT[bh][d][t] ----------------
__global__ void transpose_v(const u16* __restrict__ qkv, u16* __restrict__ vT) {
    const int bh = blockIdx.z, b = bh >> 4, hh = bh & 15;
    const int t0 = blockIdx.x * 32, d0 = blockIdx.y * 32;
    __shared__ u16 tile[32][33];
    const u16* src = qkv + (long)(b * 1024) * 3072 + 2048 + hh * 64;
    for (int i = threadIdx.y; i < 32; i += 8)
        tile[i][threadIdx.x] = src[(long)(t0 + i) * 3072 + d0 + threadIdx.x];
    __syncthreads();
    u16* dst = vT + (long)bh * 64 * 1024;
    for (int i = threadIdx.y; i < 32; i += 8)
        dst[(long)(d0 + i) * 1024 + t0 + threadIdx.x] = tile[threadIdx.x][i];
}

// ---------------- reduce Wo split-K partials + residual + LN2, fused ----------------
// hidden = sum_z part[z] + bo + x ; mbuf = ln2(hidden)
__global__ void reduce_wo_ln(const u16* __restrict__ part, const float* __restrict__ x,
                             const float* __restrict__ bo, const float* __restrict__ g,
                             const float* __restrict__ bb, float* __restrict__ hid,
                             u16* __restrict__ mbuf) {
    const int row = blockIdx.x;
    const long base = (long)row * 1024;
    const int t = threadIdx.x;
    float4 h = ((const float4*)(x + base))[t];
    float4 bo4 = ((const float4*)bo)[t];
    h.x += bo4.x; h.y += bo4.y; h.z += bo4.z; h.w += bo4.w;
#pragma unroll
    for (int z = 0; z < 4; ++z) {
        ushort4 q = ((const ushort4*)(part + (long)z * (4096L * 1024) + base))[t];
        h.x += bf2f(q.x); h.y += bf2f(q.y); h.z += bf2f(q.z); h.w += bf2f(q.w);
    }
    ((float4*)(hid + base))[t] = h;
    float s = h.x + h.y + h.z + h.w;
    float ss = h.x * h.x + h.y * h.y + h.z * h.z + h.w * h.w;
    for (int o = 32; o > 0; o >>= 1) { s += __shfl_down(s, o); ss += __shfl_down(ss, o); }
    __shared__ float red[8];
    if ((t & 63) == 0) { red[t >> 6] = s; red[(t >> 6) + 4] = ss; }
    __syncthreads();
    float sum = red[0] + red[1] + red[2] + red[3];
    float sq  = red[4] + red[5] + red[6] + red[7];
    const float mean = sum * (1.f / 1024.f);
    const float rstd = rsqrtf(sq * (1.f / 1024.f) - mean * mean + 1e-5f);
    float4 G = ((const float4*)g)[t], B = ((const float4*)bb)[t];
    ushort4 o;
    o.x = f2bf((h.x - mean) * rstd * G.x + B.x);
    o.y = f2bf((h.y - mean) * rstd * G.y + B.y);
    o.z = f2bf((h.z - mean) * rstd * G.z + B.z);
    o.w = f2bf((h.w - mean) * rstd * G.w + B.w);
    ((ushort4*)(mbuf + base))[t] = o;
}

// ---------------- final reduce: out += sum_z bf16partial[z] + b2 ----------------
__global__ void reduce_out4(float* __restrict__ out, const u16* __restrict__ p,
                            const float* __restrict__ b2) {
    const long base = (long)blockIdx.x * 1024;
    const int t = threadIdx.x;
    float4 sum = {0.f, 0.f, 0.f, 0.f};
#pragma unroll
    for (int z = 0; z < 4; ++z) {
        ushort4 q = ((const ushort4*)(p + (long)z * (4096L * 1024) + base))[t];
        sum.x += bf2f(q.x); sum.y += bf2f(q.y);
        sum.z += bf2f(q.z); sum.w += bf2f(q.w);
    }
    float4 bias = ((const float4*)b2)[t];
    float4 o = ((const float4*)(out + base))[t];
    o.x += sum.x + bias.x; o.y += sum.y + bias.y;
    o.z += sum.z + bias.z; o.w += sum.w + bias.w;
    ((float4*)(out + base))[t] = o;
}

// ---------------- gemm_256: 256x256 block tile, 4 waves (2x2), wave tile 128x128 -------------
// R9 model closed exactly: 128-tiles are LDS-total-BW bound at ~25% MfmaUtil (40 KB LDS per
// 1-MFLOP tile). 256^2 tile: 96 KB LDS per 4-MFLOP tile -> ~83 B/cy demand at full MFMA rate
// ~= the 85 B/cy ds_read_b128 ceiling -> ~50% ceiling (2x). The 1183-cy tile period also
// makes ring-2 singles prefetch sufficient: the stage drains a full compute-phase (>= HBM
// latency) after issue, so 1 block/CU no longer convoys (the R3 failure needed 310-cy tiles).
// acc = 8x8 f32x4 = 256 VGPR; launch_bounds(256,1) -> 512-VGPR cap, no spill expected (m24).
// LDS 2 x 32 KB = 64 KB. XOR swizzle identical to R7/R9 (verified).
// Requires M,N multiples of 256 covered by grid; split-K via gridDim.z; row stride ld.
template <typename Epi>
__global__ __launch_bounds__(256, 1)
void gemm_256(const u16* __restrict__ A, const u16* __restrict__ Bt,
              int K, int ld, Epi epi) {
    constexpr int AE = 256 * 32;   // u16 elems per operand slot
    __shared__ u16 sm[2][AE + AE];
    const int tid = threadIdx.x;
    const int wid = tid >> 6, lane = tid & 63;
    const int lr = lane & 15, lh = lane >> 4;
    const int m0 = blockIdx.y * 256, n0 = blockIdx.x * 256;
    const long k0g = (long)blockIdx.z * K;
    const int wm = (wid >> 1) * 128, wn = (wid & 1) * 128;

    // staging: 16 chunks per operand (16 rows x 32 k each); wave w stages chunks 4w..4w+3
    const int cr = lane >> 2, lq = lane & 3;
    long aoff[4], boff[4];
    int lA[4], lB[4];
#pragma unroll
    for (int c = 0; c < 4; ++c) {
        const int r = (wid * 4 + c) * 16 + cr;
        const int q = lq ^ (r & 3) ^ ((r >> 2) & 3);
        aoff[c] = (long)(m0 + r) * ld + k0g + q * 8;
        boff[c] = (long)(n0 + r) * ld + k0g + q * 8;
        lA[c] = (wid * 4 + c) * 512;
        lB[c] = AE + (wid * 4 + c) * 512;
    }
    const int qoff = ((lh ^ (lr & 3) ^ ((lr >> 2) & 3)) & 3) * 8;

    f32x4 acc[8][8] = {};
    const int nk = K / 32;

    auto stage = [&](int kt) {
        const long ko = (long)kt * 32;
        u16* s = sm[kt & 1];
#pragma unroll
        for (int c = 0; c < 4; ++c) {
            async_ld16(A + aoff[c] + ko, s + lA[c]);
            async_ld16(Bt + boff[c] + ko, s + lB[c]);
        }
    };
    auto compute = [&](int kt) {
        const u16* sA = sm[kt & 1];
        const u16* sB = sA + AE;
        bf16x8 bfr[8];
#pragma unroll
        for (int j = 0; j < 8; ++j)
            bfr[j] = *(const bf16x8*)(sB + (wn + j * 16 + lr) * 32 + qoff);
#pragma unroll
        for (int i = 0; i < 8; ++i) {
            bf16x8 af = *(const bf16x8*)(sA + (wm + i * 16 + lr) * 32 + qoff);
#pragma unroll
            for (int j = 0; j < 8; ++j)
                acc[i][j] = mfma16(af, bfr[j], acc[i][j]);
        }
    };

    stage(0);
    __syncthreads();
    for (int kt = 0; kt < nk; ++kt) {
        if (kt + 1 < nk) stage(kt + 1);
        compute(kt);
        __syncthreads();
    }

#pragma unroll
    for (int i = 0; i < 8; ++i)
#pragma unroll
        for (int j = 0; j < 8; ++j) {
            const int col = n0 + wn + j * 16 + lr;
#pragma unroll
            for (int r = 0; r < 4; ++r)
                epi(m0 + wm + i * 16 + lh * 4 + r, col, acc[i][j][r]);
        }
}

// ---------------- gemm_64: 128x64 block tile, 4 waves (adapter GEMMs) ----------------
template <typename Epi>
__global__ __launch_bounds__(256, 4)
void gemm_64(const u16* __restrict__ A, const u16* __restrict__ Bt,
             int N, int K, int ld, Epi epi) {
    constexpr int AE = 128 * 32;
    constexpr int BE = 64 * 32;
    __shared__ u16 sm[2][AE + BE];
    const int tid = threadIdx.x;
    const int m0 = blockIdx.y * 128;
    const int n0 = blockIdx.x * 64;
    const long k0g = (long)blockIdx.z * K;
    const int wid = tid >> 6, lane = tid & 63;
    const int lr = lane & 15, lh = lane >> 4;
    const int wm = wid * 32;

    const int cr = lane >> 2, lq = lane & 3;
    const int ra0 = wid * 32 + cr, ra1 = ra0 + 16;
    const int qa0 = lq ^ (ra0 & 3) ^ ((ra0 >> 2) & 3);
    const int qa1 = lq ^ (ra1 & 3) ^ ((ra1 >> 2) & 3);
    const long aoff0 = (long)(m0 + ra0) * ld + k0g + qa0 * 8;
    const long aoff1 = (long)(m0 + ra1) * ld + k0g + qa1 * 8;
    const int la0 = wid * 1024, la1 = la0 + 512;

    const int rb = wid * 16 + cr;
    const int qb = lq ^ (rb & 3) ^ ((rb >> 2) & 3);
    const long boff0 = (long)min(n0 + rb, N - 1) * ld + k0g + qb * 8;
    const int lb0 = AE + wid * 512;

    const int qoff = ((lh ^ (lr & 3) ^ ((lr >> 2) & 3)) & 3) * 8;

    f32x4 acc[2][4] = {};
    const int nk = K / 32;

    auto stage = [&](int kt) {
        const long ko = (long)kt * 32;
        u16* s = sm[kt & 1];
        async_ld16(A + aoff0 + ko, s + la0);
        async_ld16(A + aoff1 + ko, s + la1);
        async_ld16(Bt + boff0 + ko, s + lb0);
    };
    auto compute = [&](int kt) {
        const u16* sA = sm[kt & 1];
        const u16* sB = sA + AE;
        bf16x8 af[2], bfr[4];
#pragma unroll
        for (int i = 0; i < 2; ++i)
            af[i] = *(const bf16x8*)(sA + (wm + i * 16 + lr) * 32 + qoff);
#pragma unroll
        for (int j = 0; j < 4; ++j)
            bfr[j] = *(const bf16x8*)(sB + (j * 16 + lr) * 32 + qoff);
#pragma unroll
        for (int i = 0; i < 2; ++i)
#pragma unroll
            for (int j = 0; j < 4; ++j)
                acc[i][j] = mfma16(af[i], bfr[j], acc[i][j]);
    };

    stage(0);
    __syncthreads();
    for (int kt = 0; kt < nk; ++kt) {
        if (kt + 1 < nk) stage(kt + 1);
        compute(kt);
        __syncthreads();
    }

#pragma unroll
    for (int i = 0; i < 2; ++i)
#pragma unroll
        for (int j = 0; j < 4; ++j) {
            const int col = n0 + j * 16 + lr;
            if (col < N) {
#pragma unroll
                for (int r = 0; r < 4; ++r) {
                    const int row = m0 + wm + i * 16 + lh * 4 + r;
                    epi(row, col, acc[i][j][r]);
                }
            }
        }
}

// ---------------- epilogues ----------------
struct EpiBF16Bias {
    u16* out; const float* bias; int ldo;
    __device__ void operator()(int r, int c, float v) const {
        out[(long)r * ldo + c] = f2bf(v + bias[c]);
    }
};
struct EpiGelu {  // act_bf16 = gelu_tanh(acc + b1)
    u16* out; const float* bias;
    __device__ void operator()(int r, int c, float v) const {
        float x = v + bias[c];
        float u2 = x * (1.5957691216f + 0.0713548162726f * x * x);
        float g = x / (1.f + __expf(-u2));
        out[(long)r * 4096 + c] = f2bf(g);
    }
};
struct EpiReluBF16 {
    u16* out; const float* bias;
    __device__ void operator()(int r, int c, float v) const {
        out[(long)r * 64 + c] = f2bf(fmaxf(v + bias[c], 0.f));
    }
};
struct EpiAdapter {  // out = 2*hidden + acc + bu
    float* out; const float* bias; const float* hidden;
    __device__ void operator()(int r, int c, float v) const {
        long i = (long)r * 1024 + c; out[i] = 2.f * hidden[i] + v + bias[c];
    }
};
struct EpiStoreSplit {  // partial[z][r][c] = bf16(acc)
    u16* p;
    __device__ void operator()(int r, int c, float v) const {
        p[(long)blockIdx.z * (4096L * 1024) + (long)r * 1024 + c] = f2bf(v);
    }
};

// ---------------- causal flash attention (unchanged, verified) ----------------
__global__ __launch_bounds__(256, 2)
void attn_kernel(const u16* __restrict__ qkv, const u16* __restrict__ vT,
                 u16* __restrict__ y) {
    const int bh = blockIdx.x, b = bh >> 4, hh = bh & 15;
    const int q0 = blockIdx.y * 128;
    const int tid = threadIdx.x, wid = tid >> 6, lane = tid & 63;
    const int lr = lane & 15, lh = lane >> 4;
    const int qw = q0 + wid * 32;

    __shared__ u16 smK[64 * 72];
    __shared__ u16 smV[64 * 72];
    __shared__ u16 smP[4 * 32 * 72];
    u16* pw = smP + wid * (32 * 72);

    const u16* qbase = qkv + (long)(b * 1024) * 3072 + hh * 64;
    const u16* kbase = qbase + 1024;
    const u16* vbase = vT + (long)bh * 64 * 1024;

    bf16x8 a_q[2][2];
#pragma unroll
    for (int mt = 0; mt < 2; ++mt)
#pragma unroll
        for (int ks = 0; ks < 2; ++ks) {
            uint4 t = *(const uint4*)(qbase + (long)(qw + mt * 16 + lr) * 3072 + ks * 32 + lh * 8);
            a_q[mt][ks] = __builtin_bit_cast(bf16x8, t);
        }

    bf16x8 ones;
    { u16x8 t = {0x3F80, 0x3F80, 0x3F80, 0x3F80, 0x3F80, 0x3F80, 0x3F80, 0x3F80};
      ones = __builtin_bit_cast(bf16x8, t); }

    f32x4 o_acc[2][4] = {};
    f32x4 l_acc[2] = {};
    f32x4 m_run[2] = {{-1e30f, -1e30f, -1e30f, -1e30f}, {-1e30f, -1e30f, -1e30f, -1e30f}};

    const int ntiles = q0 / 64 + 2;
    const int ck = tid >> 3, cs = (tid & 7) * 8;
    const int ck2 = (tid + 256) >> 3, cs2 = ((tid + 256) & 7) * 8;
    for (int kt = 0; kt < ntiles; ++kt) {
        const int k0 = kt * 64;
        __syncthreads();
        {
            uint4 kv0 = *(const uint4*)(kbase + (long)(k0 + ck) * 3072 + cs);
            uint4 kv1 = *(const uint4*)(kbase + (long)(k0 + ck2) * 3072 + cs2);
            *(uint4*)(smK + ck * 72 + cs) = kv0;
            *(uint4*)(smK + ck2 * 72 + cs2) = kv1;
            uint4 vv0 = *(const uint4*)(vbase + (long)ck * 1024 + k0 + cs);
            uint4 vv1 = *(const uint4*)(vbase + (long)ck2 * 1024 + k0 + cs2);
            *(uint4*)(smV + ck * 72 + cs) = vv0;
            *(uint4*)(smV + ck2 * 72 + cs2) = vv1;
        }
        __syncthreads();
        if (k0 > qw + 31) continue;

        bf16x8 bK[4][2];
#pragma unroll
        for (int nt = 0; nt < 4; ++nt)
#pragma unroll
            for (int ks = 0; ks < 2; ++ks)
                bK[nt][ks] = *(const bf16x8*)(smK + (nt * 16 + lr) * 72 + ks * 32 + lh * 8);

        f32x4 s[2][4];
#pragma unroll
        for (int mt = 0; mt < 2; ++mt)
#pragma unroll
            for (int nt = 0; nt < 4; ++nt) {
                f32x4 z = {0.f, 0.f, 0.f, 0.f};
                z = mfma16(a_q[mt][0], bK[nt][0], z);
                z = mfma16(a_q[mt][1], bK[nt][1], z);
                s[mt][nt] = z;
            }
#pragma unroll
        for (int mt = 0; mt < 2; ++mt) {
            const int qb = qw + mt * 16 + lh * 4;
#pragma unroll
            for (int nt = 0; nt < 4; ++nt) {
                const int kkg = k0 + nt * 16 + lr;
#pragma unroll
                for (int r = 0; r < 4; ++r) {
                    float v = s[mt][nt][r] * 0.125f;
                    if (kkg > qb + r) v = -1e30f;
                    s[mt][nt][r] = v;
                }
            }
        }
#pragma unroll
        for (int mt = 0; mt < 2; ++mt) {
            f32x4 mx = s[mt][0];
#pragma unroll
            for (int nt = 1; nt < 4; ++nt)
#pragma unroll
                for (int r = 0; r < 4; ++r) mx[r] = fmaxf(mx[r], s[mt][nt][r]);
#pragma unroll
            for (int xm = 1; xm < 16; xm <<= 1)
#pragma unroll
                for (int r = 0; r < 4; ++r) mx[r] = fmaxf(mx[r], __shfl_xor(mx[r], xm));
            f32x4 mnew, alpha;
#pragma unroll
            for (int r = 0; r < 4; ++r) {
                mnew[r] = fmaxf(m_run[mt][r], mx[r]);
                alpha[r] = __expf(m_run[mt][r] - mnew[r]);
            }
            m_run[mt] = mnew;
            l_acc[mt] *= alpha;
#pragma unroll
            for (int dt = 0; dt < 4; ++dt) o_acc[mt][dt] *= alpha;
#pragma unroll
            for (int nt = 0; nt < 4; ++nt)
#pragma unroll
                for (int r = 0; r < 4; ++r)
                    s[mt][nt][r] = __expf(s[mt][nt][r] - mnew[r]);
#pragma unroll
            for (int nt = 0; nt < 4; ++nt)
#pragma unroll
                for (int r = 0; r < 4; ++r)
                    pw[(mt * 16 + lh * 4 + r) * 72 + nt * 16 + lr] = f2bf(s[mt][nt][r]);
        }
        bf16x8 vf[4][2];
#pragma unroll
        for (int dt = 0; dt < 4; ++dt)
#pragma unroll
            for (int ks = 0; ks < 2; ++ks)
                vf[dt][ks] = *(const bf16x8*)(smV + (dt * 16 + lr) * 72 + ks * 32 + lh * 8);
#pragma unroll
        for (int mt = 0; mt < 2; ++mt) {
            bf16x8 pf0 = *(const bf16x8*)(pw + (mt * 16 + lr) * 72 + lh * 8);
            bf16x8 pf1 = *(const bf16x8*)(pw + (mt * 16 + lr) * 72 + 32 + lh * 8);
            l_acc[mt] = mfma16(pf0, ones, l_acc[mt]);
            l_acc[mt] = mfma16(pf1, ones, l_acc[mt]);
#pragma unroll
            for (int dt = 0; dt < 4; ++dt) {
                o_acc[mt][dt] = mfma16(pf0, vf[dt][0], o_acc[mt][dt]);
                o_acc[mt][dt] = mfma16(pf1, vf[dt][1], o_acc[mt][dt]);
            }
        }
    }
#pragma unroll
    for (int mt = 0; mt < 2; ++mt) {
        f32x4 linv;
#pragma unroll
        for (int r = 0; r < 4; ++r) linv[r] = 1.f / l_acc[mt][r];
#pragma unroll
        for (int dt = 0; dt < 4; ++dt) {
#pragma unroll
            for (int r = 0; r < 4; ++r) {
                const int tok = b * 1024 + qw + mt * 16 + lh * 4 + r;
                y[(long)tok * 1024 + hh * 64 + dt * 16 + lr] = f2bf(o_acc[mt][dt][r] * linv[r]);
            }
        }
    }
}

// ---------------- launch ----------------
extern "C" void kernel_launch(void* const* d_in, const int* in_sizes, int n_in,
                              void* d_out, int out_size, void* d_ws, size_t ws_size,
                              hipStream_t stream) {
    const float* x    = (const float*)d_in[0];
    const float* ln1g = (const float*)d_in[1];
    const float* ln1b = (const float*)d_in[2];
    const float* ln2g = (const float*)d_in[3];
    const float* ln2b = (const float*)d_in[4];
    const float* ln3g = (const float*)d_in[5];
    const float* ln3b = (const float*)d_in[6];
    const float* wq = (const float*)d_in[7];  const float* bq = (const float*)d_in[8];
    const float* wk = (const float*)d_in[9];  const float* bk = (const float*)d_in[10];
    const float* wv = (const float*)d_in[11]; const float* bv = (const float*)d_in[12];
    const float* wo = (const float*)d_in[13]; const float* bo = (const float*)d_in[14];
    const float* w1 = (const float*)d_in[15]; const float* b1 = (const float*)d_in[16];
    const float* w2 = (const float*)d_in[17]; const float* b2 = (const float*)d_in[18];
    const float* wd = (const float*)d_in[19]; const float* bd = (const float*)d_in[20];
    const float* wu = (const float*)d_in[21]; const float* bu = (const float*)d_in[22];
    float* out = (float*)d_out;

    char* base = (char*)d_ws;
    size_t off = 0;
    auto carve = [&](size_t bytes) -> char* {
        char* p = base + off; off += (bytes + 255) & ~(size_t)255; return p;
    };
    u16* qkv_wt = (u16*)carve(3072L * 1024 * 2);
    u16* wo_t   = (u16*)carve(1024L * 1024 * 2);
    u16* w1_t   = (u16*)carve(4096L * 1024 * 2);
    u16* w2_t   = (u16*)carve(1024L * 4096 * 2);
    u16* wd_t   = (u16*)carve(64L * 1024 * 2);
    u16* wu_t   = (u16*)carve(1024L * 64 * 2);
    float* bqkv = (float*)carve(3072L * 4);
    u16* hbuf   = (u16*)carve(4096L * 1024 * 2);
    u16* nrm    = (u16*)carve(4096L * 1024 * 2);
    u16* qkvb   = (u16*)carve(4096L * 3072 * 2);
    u16* vT     = (u16*)carve(64L * 64 * 1024 * 2);
    u16* ybuf   = (u16*)carve(4096L * 1024 * 2);
    float* hid  = (float*)carve(4096L * 1024 * 4);
    u16* mbuf   = (u16*)carve(4096L * 1024 * 2);
    u16* act    = (u16*)carve(4096L * 4096 * 2);
    u16* t1     = (u16*)carve(4096L * 64 * 2);
    u16* part   = (u16*)carve(4L * 4096 * 1024 * 2);  // split-K bf16 partials (Wo, then MLP2)

    // prep: 8 weight transposes + qkv bias concat + LN1/LN3
    PrepParams pp;
    pp.src[0] = wq; pp.dst[0] = qkv_wt;                 pp.K[0] = 1024; pp.N[0] = 1024;
    pp.src[1] = wk; pp.dst[1] = qkv_wt + 1024L * 1024;  pp.K[1] = 1024; pp.N[1] = 1024;
    pp.src[2] = wv; pp.dst[2] = qkv_wt + 2048L * 1024;  pp.K[2] = 1024; pp.N[2] = 1024;
    pp.src[3] = wo; pp.dst[3] = wo_t;                   pp.K[3] = 1024; pp.N[3] = 1024;
    pp.src[4] = w1; pp.dst[4] = w1_t;                   pp.K[4] = 1024; pp.N[4] = 4096;
    pp.src[5] = w2; pp.dst[5] = w2_t;                   pp.K[5] = 4096; pp.N[5] = 1024;
    pp.src[6] = wd; pp.dst[6] = wd_t;                   pp.K[6] = 1024; pp.N[6] = 64;
    pp.src[7] = wu; pp.dst[7] = wu_t;                   pp.K[7] = 64;   pp.N[7] = 1024;
    int acc_blocks = 0;
    for (int j = 0; j < 8; ++j) {
        pp.pfx[j] = acc_blocks;
        acc_blocks += (pp.N[j] >> 6) * (pp.K[j] >> 6);
    }
    pp.pfx[8] = acc_blocks;
    pp.bq = bq; pp.bk = bk; pp.bv = bv; pp.bqkv = bqkv;
    pp.x = x; pp.g1 = ln1g; pp.b1 = ln1b; pp.g3 = ln3g; pp.b3 = ln3b;
    pp.o1 = hbuf; pp.o3 = nrm;
    prep_kernel<<<acc_blocks + 12 + 4096, 256, 0, stream>>>(pp);

    // QKV: 256^2 tiles, grid 12x16
    gemm_256<<<dim3(12, 16), 256, 0, stream>>>(hbuf, qkv_wt, 1024, 1024,
                                               EpiBF16Bias{qkvb, bqkv, 3072});
    transpose_v<<<dim3(32, 2, 64), dim3(32, 8), 0, stream>>>(qkvb, vT);
    attn_kernel<<<dim3(64, 8), 256, 0, stream>>>(qkvb, vT, ybuf);
    // Wo: split-K x4 -> bf16 partials, then fused reduce + residual + LN2
    gemm_256<<<dim3(4, 16, 4), 256, 0, stream>>>(ybuf, wo_t, 256, 1024,
                                                 EpiStoreSplit{part});
    reduce_wo_ln<<<4096, 256, 0, stream>>>(part, x, bo, ln2g, ln2b, hid, mbuf);
    // MLP1: grid 16x16 = 256 blocks = 1/CU
    gemm_256<<<dim3(16, 16), 256, 0, stream>>>(mbuf, w1_t, 1024, 1024,
                                               EpiGelu{act, b1});
    // adapter
    gemm_64<<<dim3(1, 32), 256, 0, stream>>>(nrm, wd_t, 64, 1024, 1024,
                                             EpiReluBF16{t1, bd});
    gemm_64<<<dim3(16, 32), 256, 0, stream>>>(t1, wu_t, 1024, 64, 64,
                                              EpiAdapter{out, bu, hid});
    // MLP2: split-K x4 -> bf16 partials, then reduce
    gemm_256<<<dim3(4, 16, 4), 256, 0, stream>>>(act, w2_t, 1024, 4096,
                                                 EpiStoreSplit{part});
    reduce_out4<<<4096, 256, 0, stream>>>(out, part, b2);
}

// Round 11
// 392.776 us; speedup vs baseline: 1.0735x; 1.0735x over previous
//
#include <hip/hip_runtime.h>

typedef unsigned short u16;
typedef __bf16 bf16x8 __attribute__((ext_vector_type(8)));
typedef u16    u16x8  __attribute__((ext_vector_type(8)));
typedef float  f32x4  __attribute__((ext_vector_type(4)));

__device__ __forceinline__ u16 f2bf(float f) {
    union { float f; unsigned u; } x{f};
    unsigned r = x.u + 0x7fffu + ((x.u >> 16) & 1u);
    return (u16)(r >> 16);
}
__device__ __forceinline__ float bf2f(u16 h) {
    union { unsigned u; float f; } x{(unsigned)h << 16};
    return x.f;
}

__device__ __forceinline__ f32x4 mfma16(bf16x8 a, bf16x8 b, f32x4 c) {
    return __builtin_amdgcn_mfma_f32_16x16x32_bf16(a, b, c, 0, 0, 0);
}

// async global->LDS, 16B per lane; LDS dest is wave-uniform base + lane*16
__device__ __forceinline__ void async_ld16(const void* g, void* l) {
    __builtin_amdgcn_global_load_lds(
        (const __attribute__((address_space(1))) unsigned int*)g,
        (__attribute__((address_space(3))) unsigned int*)l, 16, 0, 0);
}

// ---------------- unified prep: weight transposes + bias concat + LN1/LN3, ONE dispatch -----
struct PrepParams {
    const float* src[8];
    u16* dst[8];
    int K[8], N[8];
    int pfx[9];
    const float *bq, *bk, *bv;
    float* bqkv;
    const float *x, *g1, *b1, *g3, *b3;
    u16 *o1, *o3;    // hbuf (ln1), nrm (ln3)
};

__global__ void prep_kernel(PrepParams p) {
    const int b = blockIdx.x;
    const int t = threadIdx.x;
    __shared__ float tile[64][65];
    __shared__ float red[8];

    if (b >= p.pfx[8] + 12) {   // LN1+LN3 tail (4096 blocks, one row each)
        const int row = b - p.pfx[8] - 12;
        const long base = (long)row * 1024;
        float4 v = ((const float4*)(p.x + base))[t];
        float s = v.x + v.y + v.z + v.w;
        float ss = v.x * v.x + v.y * v.y + v.z * v.z + v.w * v.w;
        for (int o = 32; o > 0; o >>= 1) { s += __shfl_down(s, o); ss += __shfl_down(ss, o); }
        if ((t & 63) == 0) { red[t >> 6] = s; red[(t >> 6) + 4] = ss; }
        __syncthreads();
        float sum = red[0] + red[1] + red[2] + red[3];
        float sq  = red[4] + red[5] + red[6] + red[7];
        const float mean = sum * (1.f / 1024.f);
        const float rstd = rsqrtf(sq * (1.f / 1024.f) - mean * mean + 1e-5f);
        float4 G1 = ((const float4*)p.g1)[t], B1 = ((const float4*)p.b1)[t];
        float4 G3 = ((const float4*)p.g3)[t], B3 = ((const float4*)p.b3)[t];
        float n0 = (v.x - mean) * rstd, n1 = (v.y - mean) * rstd;
        float n2 = (v.z - mean) * rstd, n3 = (v.w - mean) * rstd;
        ushort4 o1, o3;
        o1.x = f2bf(n0 * G1.x + B1.x); o1.y = f2bf(n1 * G1.y + B1.y);
        o1.z = f2bf(n2 * G1.z + B1.z); o1.w = f2bf(n3 * G1.w + B1.w);
        o3.x = f2bf(n0 * G3.x + B3.x); o3.y = f2bf(n1 * G3.y + B3.y);
        o3.z = f2bf(n2 * G3.z + B3.z); o3.w = f2bf(n3 * G3.w + B3.w);
        ((ushort4*)(p.o1 + base))[t] = o1;
        ((ushort4*)(p.o3 + base))[t] = o3;
        return;
    }
    if (b >= p.pfx[8]) {        // bias-concat tail
        int i = (b - p.pfx[8]) * 256 + t;
        p.bqkv[i] = i < 1024 ? p.bq[i] : (i < 2048 ? p.bk[i - 1024] : p.bv[i - 2048]);
        return;
    }
    int j = 0;
    while (b >= p.pfx[j + 1]) ++j;
    const float* __restrict__ in = p.src[j];
    u16* __restrict__ out = p.dst[j];
    const int K = p.K[j], N = p.N[j];
    const int local = b - p.pfx[j];
    const int tx = N >> 6;
    const int n0 = (local % tx) * 64, k0 = (local / tx) * 64;
    const int rr = t >> 4, cc = t & 15;
#pragma unroll
    for (int it = 0; it < 4; ++it) {
        const int r = rr + it * 16;
        float4 v = *(const float4*)(in + (long)(k0 + r) * N + n0 + cc * 4);
        tile[r][cc * 4 + 0] = v.x; tile[r][cc * 4 + 1] = v.y;
        tile[r][cc * 4 + 2] = v.z; tile[r][cc * 4 + 3] = v.w;
    }
    __syncthreads();
#pragma unroll
    for (int it = 0; it < 4; ++it) {
        const int n = rr + it * 16;
        ushort4 o;
        o.x = f2bf(tile[cc * 4 + 0][n]);
        o.y = f2bf(tile[cc * 4 + 1][n]);
        o.z = f2bf(tile[cc * 4 + 2][n]);
        o.w = f2bf(tile[cc * 4 + 3][n]);
        *(ushort4*)(out + (long)(n0 + n) * K + k0 + cc * 4) = o;
    }
}

// ---------------- LN2 (after Wo residual) ----------------
__global__ void ln_single_kernel(const float* __restrict__ x,
                                 const float* __restrict__ g, const float* __restrict__ b,
                                 u16* __restrict__ out) {
    const int row = blockIdx.x;
    const long base = (long)row * 1024;
    const int t = threadIdx.x;
    float4 v = ((const float4*)(x + base))[t];
    float s = v.x + v.y + v.z + v.w;
    float ss = v.x * v.x + v.y * v.y + v.z * v.z + v.w * v.w;
    for (int o = 32; o > 0; o >>= 1) { s += __shfl_down(s, o); ss += __shfl_down(ss, o); }
    __shared__ float red[8];
    if ((t & 63) == 0) { red[t >> 6] = s; red[(t >> 6) + 4] = ss; }
    __syncthreads();
    float sum = red[0] + red[1] + red[2] + red[3];
    float sq  = red[4] + red[5] + red[6] + red[7];
    const float mean = sum * (1.f / 1024.f);
    const float rstd = rsqrtf(sq * (1.f / 1024.f) - mean * mean + 1e-5f);
    float4 G = ((const float4*)g)[t], B = ((const float4*)b)[t];
    ushort4 o;
    o.x = f2bf((v.x - mean) * rstd * G.x + B.x);
    o.y = f2bf((v.y - mean) * rstd * G.y + B.y);
    o.z = f2bf((v.z - mean) * rstd * G.z + B.z);
    o.w = f2bf((v.w - mean) * rstd * G.w + B.w);
    ((ushort4*)(out + base))[t] = o;
}

// ---------------- V transpose: qkv[tok][2048+h*64+d] -> vT[bh][d][t] ----------------
__global__ void transpose_v(const u16* __restrict__ qkv, u16* __restrict__ vT) {
    const int bh = blockIdx.z, b = bh >> 4, hh = bh & 15;
    const int t0 = blockIdx.x * 32, d0 = blockIdx.y * 32;
    __shared__ u16 tile[32][33];
    const u16* src = qkv + (long)(b * 1024) * 3072 + 2048 + hh * 64;
    for (int i = threadIdx.y; i < 32; i += 8)
        tile[i][threadIdx.x] = src[(long)(t0 + i) * 3072 + d0 + threadIdx.x];
    __syncthreads();
    u16* dst = vT + (long)bh * 64 * 1024;
    for (int i = threadIdx.y; i < 32; i += 8)
        dst[(long)(d0 + i) * 1024 + t0 + threadIdx.x] = tile[threadIdx.x][i];
}

// ---------------- final reduce: out += sum_z bf16partial[z] + b2 ----------------
__global__ void reduce_out4(float* __restrict__ out, const u16* __restrict__ p,
                            const float* __restrict__ b2) {
    const long base = (long)blockIdx.x * 1024;
    const int t = threadIdx.x;
    float4 sum = {0.f, 0.f, 0.f, 0.f};
#pragma unroll
    for (int z = 0; z < 4; ++z) {
        ushort4 q = ((const ushort4*)(p + (long)z * (4096L * 1024) + base))[t];
        sum.x += bf2f(q.x); sum.y += bf2f(q.y);
        sum.z += bf2f(q.z); sum.w += bf2f(q.w);
    }
    float4 bias = ((const float4*)b2)[t];
    float4 o = ((const float4*)(out + base))[t];
    o.x += sum.x + bias.x; o.y += sum.y + bias.y;
    o.z += sum.z + bias.z; o.w += sum.w + bias.w;
    ((float4*)(out + base))[t] = o;
}

// ---------------- gemm_big: 128x128 block tile, 2 waves, wave tile 128x64 ----------------
// R9's best GEMM (24.7% MfmaUtil). R11 adds an XCD-aware block swizzle: R9 counters showed
// FETCH_SIZE=145 MB (9x unique footprint) at 3.2 TB/s — every XCD's private L2 streamed the
// full A and B. With dispatch id2d = bx + Gx*by and XCD ~= id2d%8 (round-robin heuristic),
// remap so XCD c owns a contiguous (Gx/4)x(Gy/2) sub-grid: per-XCD footprint drops to
// A/2 + B/4, turning HBM-latency misses (~900cy, longer than the ring-2 prefetch distance)
// into L2/L3 hits (~200cy). Requires Gx%4==0, Gy%2==0 (all call sites comply).
// LDS XOR-swizzle (verified): row r, logical k-quarter q at phys slot q^(r&3)^((r>>2)&3);
// folded into the per-lane GLOBAL fetch address. Split-K via gridDim.z; row stride ld.
template <typename Epi>
__global__ __launch_bounds__(128, 2)
void gemm_big(const u16* __restrict__ A, const u16* __restrict__ Bt,
              int N, int K, int ld, Epi epi) {
    constexpr int AE = 128 * 32;
    __shared__ u16 sm[2][AE + AE];
    const int tid = threadIdx.x;
    const int wid = tid >> 6, lane = tid & 63;
    const int lr = lane & 15, lh = lane >> 4;

    // XCD-aware swizzle
    const int Gx = gridDim.x, Gy = gridDim.y;
    const int id2d = blockIdx.x + Gx * blockIdx.y;
    const int c8 = id2d & 7, l = id2d >> 3;
    const int sx = Gx >> 2;                       // region width (x)
    const int bx = (c8 & 3) * sx + l % sx;
    const int by = (c8 >> 2) * (Gy >> 1) + l / sx;
    const int m0 = by * 128, n0 = bx * 128;
    const long k0g = (long)blockIdx.z * K;
    const int wn = wid * 64;

    const int cr = lane >> 2, lq = lane & 3;
    long aoff[4], boff[4];
    int lA[4], lB[4];
#pragma unroll
    for (int c = 0; c < 4; ++c) {
        const int r = wid * 64 + c * 16 + cr;
        const int q = lq ^ (r & 3) ^ ((r >> 2) & 3);
        aoff[c] = (long)(m0 + r) * ld + k0g + q * 8;
        boff[c] = (long)(n0 + r) * ld + k0g + q * 8;
        lA[c] = (wid * 4 + c) * 512;
        lB[c] = AE + (wid * 4 + c) * 512;
    }
    const int qoff = ((lh ^ (lr & 3) ^ ((lr >> 2) & 3)) & 3) * 8;

    f32x4 acc[8][4] = {};
    const int nk = K / 32;

    auto stage = [&](int kt) {
        const long ko = (long)kt * 32;
        u16* s = sm[kt & 1];
#pragma unroll
        for (int c = 0; c < 4; ++c) {
            async_ld16(A + aoff[c] + ko, s + lA[c]);
            async_ld16(Bt + boff[c] + ko, s + lB[c]);
        }
    };
    auto compute = [&](int kt) {
        const u16* sA = sm[kt & 1];
        const u16* sB = sA + AE;
        bf16x8 bfr[4];
#pragma unroll
        for (int j = 0; j < 4; ++j)
            bfr[j] = *(const bf16x8*)(sB + (wn + j * 16 + lr) * 32 + qoff);
#pragma unroll
        for (int i = 0; i < 8; ++i) {
            bf16x8 af = *(const bf16x8*)(sA + (i * 16 + lr) * 32 + qoff);
#pragma unroll
            for (int j = 0; j < 4; ++j)
                acc[i][j] = mfma16(af, bfr[j], acc[i][j]);
        }
    };

    stage(0);
    __syncthreads();
    for (int kt = 0; kt < nk; ++kt) {
        if (kt + 1 < nk) stage(kt + 1);
        compute(kt);
        __syncthreads();
    }

#pragma unroll
    for (int i = 0; i < 8; ++i)
#pragma unroll
        for (int j = 0; j < 4; ++j) {
            const int col = n0 + wn + j * 16 + lr;
#pragma unroll
            for (int r = 0; r < 4; ++r)
                epi(m0 + i * 16 + lh * 4 + r, col, acc[i][j][r]);
        }
}

// ---------------- gemm_64: 128x64 block tile, 4 waves (Wo + adapter GEMMs) ----------------
template <typename Epi>
__global__ __launch_bounds__(256, 4)
void gemm_64(const u16* __restrict__ A, const u16* __restrict__ Bt,
             int N, int K, int ld, Epi epi) {
    constexpr int AE = 128 * 32;
    constexpr int BE = 64 * 32;
    __shared__ u16 sm[2][AE + BE];
    const int tid = threadIdx.x;
    const int m0 = blockIdx.y * 128;
    const int n0 = blockIdx.x * 64;
    const long k0g = (long)blockIdx.z * K;
    const int wid = tid >> 6, lane = tid & 63;
    const int lr = lane & 15, lh = lane >> 4;
    const int wm = wid * 32;

    const int cr = lane >> 2, lq = lane & 3;
    const int ra0 = wid * 32 + cr, ra1 = ra0 + 16;
    const int qa0 = lq ^ (ra0 & 3) ^ ((ra0 >> 2) & 3);
    const int qa1 = lq ^ (ra1 & 3) ^ ((ra1 >> 2) & 3);
    const long aoff0 = (long)(m0 + ra0) * ld + k0g + qa0 * 8;
    const long aoff1 = (long)(m0 + ra1) * ld + k0g + qa1 * 8;
    const int la0 = wid * 1024, la1 = la0 + 512;

    const int rb = wid * 16 + cr;
    const int qb = lq ^ (rb & 3) ^ ((rb >> 2) & 3);
    const long boff0 = (long)min(n0 + rb, N - 1) * ld + k0g + qb * 8;
    const int lb0 = AE + wid * 512;

    const int qoff = ((lh ^ (lr & 3) ^ ((lr >> 2) & 3)) & 3) * 8;

    f32x4 acc[2][4] = {};
    const int nk = K / 32;

    auto stage = [&](int kt) {
        const long ko = (long)kt * 32;
        u16* s = sm[kt & 1];
        async_ld16(A + aoff0 + ko, s + la0);
        async_ld16(A + aoff1 + ko, s + la1);
        async_ld16(Bt + boff0 + ko, s + lb0);
    };
    auto compute = [&](int kt) {
        const u16* sA = sm[kt & 1];
        const u16* sB = sA + AE;
        bf16x8 af[2], bfr[4];
#pragma unroll
        for (int i = 0; i < 2; ++i)
            af[i] = *(const bf16x8*)(sA + (wm + i * 16 + lr) * 32 + qoff);
#pragma unroll
        for (int j = 0; j < 4; ++j)
            bfr[j] = *(const bf16x8*)(sB + (j * 16 + lr) * 32 + qoff);
#pragma unroll
        for (int i = 0; i < 2; ++i)
#pragma unroll
            for (int j = 0; j < 4; ++j)
                acc[i][j] = mfma16(af[i], bfr[j], acc[i][j]);
    };

    stage(0);
    __syncthreads();
    for (int kt = 0; kt < nk; ++kt) {
        if (kt + 1 < nk) stage(kt + 1);
        compute(kt);
        __syncthreads();
    }

#pragma unroll
    for (int i = 0; i < 2; ++i)
#pragma unroll
        for (int j = 0; j < 4; ++j) {
            const int col = n0 + j * 16 + lr;
            if (col < N) {
#pragma unroll
                for (int r = 0; r < 4; ++r) {
                    const int row = m0 + wm + i * 16 + lh * 4 + r;
                    epi(row, col, acc[i][j][r]);
                }
            }
        }
}

// ---------------- epilogues ----------------
struct EpiBF16Bias {
    u16* out; const float* bias; int ldo;
    __device__ void operator()(int r, int c, float v) const {
        out[(long)r * ldo + c] = f2bf(v + bias[c]);
    }
};
struct EpiResid {  // hidden = acc + bo + x
    float* hidden; const float* bias; const float* x;
    __device__ void operator()(int r, int c, float v) const {
        long i = (long)r * 1024 + c; hidden[i] = v + bias[c] + x[i];
    }
};
struct EpiGelu {  // act_bf16 = gelu_tanh(acc + b1)
    u16* out; const float* bias;
    __device__ void operator()(int r, int c, float v) const {
        float x = v + bias[c];
        float u2 = x * (1.5957691216f + 0.0713548162726f * x * x);
        float g = x / (1.f + __expf(-u2));
        out[(long)r * 4096 + c] = f2bf(g);
    }
};
struct EpiReluBF16 {
    u16* out; const float* bias;
    __device__ void operator()(int r, int c, float v) const {
        out[(long)r * 64 + c] = f2bf(fmaxf(v + bias[c], 0.f));
    }
};
struct EpiAdapter {  // out = 2*hidden + acc + bu
    float* out; const float* bias; const float* hidden;
    __device__ void operator()(int r, int c, float v) const {
        long i = (long)r * 1024 + c; out[i] = 2.f * hidden[i] + v + bias[c];
    }
};
struct EpiStoreSplit {  // partial[z][r][c] = bf16(acc)
    u16* p;
    __device__ void operator()(int r, int c, float v) const {
        p[(long)blockIdx.z * (4096L * 1024) + (long)r * 1024 + c] = f2bf(v);
    }
};

// ---------------- causal flash attention (unchanged, verified) ----------------
__global__ __launch_bounds__(256, 2)
void attn_kernel(const u16* __restrict__ qkv, const u16* __restrict__ vT,
                 u16* __restrict__ y) {
    const int bh = blockIdx.x, b = bh >> 4, hh = bh & 15;
    const int q0 = blockIdx.y * 128;
    const int tid = threadIdx.x, wid = tid >> 6, lane = tid & 63;
    const int lr = lane & 15, lh = lane >> 4;
    const int qw = q0 + wid * 32;

    __shared__ u16 smK[64 * 72];
    __shared__ u16 smV[64 * 72];
    __shared__ u16 smP[4 * 32 * 72];
    u16* pw = smP + wid * (32 * 72);

    const u16* qbase = qkv + (long)(b * 1024) * 3072 + hh * 64;
    const u16* kbase = qbase + 1024;
    const u16* vbase = vT + (long)bh * 64 * 1024;

    bf16x8 a_q[2][2];
#pragma unroll
    for (int mt = 0; mt < 2; ++mt)
#pragma unroll
        for (int ks = 0; ks < 2; ++ks) {
            uint4 t = *(const uint4*)(qbase + (long)(qw + mt * 16 + lr) * 3072 + ks * 32 + lh * 8);
            a_q[mt][ks] = __builtin_bit_cast(bf16x8, t);
        }

    bf16x8 ones;
    { u16x8 t = {0x3F80, 0x3F80, 0x3F80, 0x3F80, 0x3F80, 0x3F80, 0x3F80, 0x3F80};
      ones = __builtin_bit_cast(bf16x8, t); }

    f32x4 o_acc[2][4] = {};
    f32x4 l_acc[2] = {};
    f32x4 m_run[2] = {{-1e30f, -1e30f, -1e30f, -1e30f}, {-1e30f, -1e30f, -1e30f, -1e30f}};

    const int ntiles = q0 / 64 + 2;
    const int ck = tid >> 3, cs = (tid & 7) * 8;
    const int ck2 = (tid + 256) >> 3, cs2 = ((tid + 256) & 7) * 8;
    for (int kt = 0; kt < ntiles; ++kt) {
        const int k0 = kt * 64;
        __syncthreads();
        {
            uint4 kv0 = *(const uint4*)(kbase + (long)(k0 + ck) * 3072 + cs);
            uint4 kv1 = *(const uint4*)(kbase + (long)(k0 + ck2) * 3072 + cs2);
            *(uint4*)(smK + ck * 72 + cs) = kv0;
            *(uint4*)(smK + ck2 * 72 + cs2) = kv1;
            uint4 vv0 = *(const uint4*)(vbase + (long)ck * 1024 + k0 + cs);
            uint4 vv1 = *(const uint4*)(vbase + (long)ck2 * 1024 + k0 + cs2);
            *(uint4*)(smV + ck * 72 + cs) = vv0;
            *(uint4*)(smV + ck2 * 72 + cs2) = vv1;
        }
        __syncthreads();
        if (k0 > qw + 31) continue;

        bf16x8 bK[4][2];
#pragma unroll
        for (int nt = 0; nt < 4; ++nt)
#pragma unroll
            for (int ks = 0; ks < 2; ++ks)
                bK[nt][ks] = *(const bf16x8*)(smK + (nt * 16 + lr) * 72 + ks * 32 + lh * 8);

        f32x4 s[2][4];
#pragma unroll
        for (int mt = 0; mt < 2; ++mt)
#pragma unroll
            for (int nt = 0; nt < 4; ++nt) {
                f32x4 z = {0.f, 0.f, 0.f, 0.f};
                z = mfma16(a_q[mt][0], bK[nt][0], z);
                z = mfma16(a_q[mt][1], bK[nt][1], z);
                s[mt][nt] = z;
            }
#pragma unroll
        for (int mt = 0; mt < 2; ++mt) {
            const int qb = qw + mt * 16 + lh * 4;
#pragma unroll
            for (int nt = 0; nt < 4; ++nt) {
                const int kkg = k0 + nt * 16 + lr;
#pragma unroll
                for (int r = 0; r < 4; ++r) {
                    float v = s[mt][nt][r] * 0.125f;
                    if (kkg > qb + r) v = -1e30f;
                    s[mt][nt][r] = v;
                }
            }
        }
#pragma unroll
        for (int mt = 0; mt < 2; ++mt) {
            f32x4 mx = s[mt][0];
#pragma unroll
            for (int nt = 1; nt < 4; ++nt)
#pragma unroll
                for (int r = 0; r < 4; ++r) mx[r] = fmaxf(mx[r], s[mt][nt][r]);
#pragma unroll
            for (int xm = 1; xm < 16; xm <<= 1)
#pragma unroll
                for (int r = 0; r < 4; ++r) mx[r] = fmaxf(mx[r], __shfl_xor(mx[r], xm));
            f32x4 mnew, alpha;
#pragma unroll
            for (int r = 0; r < 4; ++r) {
                mnew[r] = fmaxf(m_run[mt][r], mx[r]);
                alpha[r] = __expf(m_run[mt][r] - mnew[r]);
            }
            m_run[mt] = mnew;
            l_acc[mt] *= alpha;
#pragma unroll
            for (int dt = 0; dt < 4; ++dt) o_acc[mt][dt] *= alpha;
#pragma unroll
            for (int nt = 0; nt < 4; ++nt)
#pragma unroll
                for (int r = 0; r < 4; ++r)
                    s[mt][nt][r] = __expf(s[mt][nt][r] - mnew[r]);
#pragma unroll
            for (int nt = 0; nt < 4; ++nt)
#pragma unroll
                for (int r = 0; r < 4; ++r)
                    pw[(mt * 16 + lh * 4 + r) * 72 + nt * 16 + lr] = f2bf(s[mt][nt][r]);
        }
        bf16x8 vf[4][2];
#pragma unroll
        for (int dt = 0; dt < 4; ++dt)
#pragma unroll
            for (int ks = 0; ks < 2; ++ks)
                vf[dt][ks] = *(const bf16x8*)(smV + (dt * 16 + lr) * 72 + ks * 32 + lh * 8);
#pragma unroll
        for (int mt = 0; mt < 2; ++mt) {
            bf16x8 pf0 = *(const bf16x8*)(pw + (mt * 16 + lr) * 72 + lh * 8);
            bf16x8 pf1 = *(const bf16x8*)(pw + (mt * 16 + lr) * 72 + 32 + lh * 8);
            l_acc[mt] = mfma16(pf0, ones, l_acc[mt]);
            l_acc[mt] = mfma16(pf1, ones, l_acc[mt]);
#pragma unroll
            for (int dt = 0; dt < 4; ++dt) {
                o_acc[mt][dt] = mfma16(pf0, vf[dt][0], o_acc[mt][dt]);
                o_acc[mt][dt] = mfma16(pf1, vf[dt][1], o_acc[mt][dt]);
            }
        }
    }
#pragma unroll
    for (int mt = 0; mt < 2; ++mt) {
        f32x4 linv;
#pragma unroll
        for (int r = 0; r < 4; ++r) linv[r] = 1.f / l_acc[mt][r];
#pragma unroll
        for (int dt = 0; dt < 4; ++dt) {
#pragma unroll
            for (int r = 0; r < 4; ++r) {
                const int tok = b * 1024 + qw + mt * 16 + lh * 4 + r;
                y[(long)tok * 1024 + hh * 64 + dt * 16 + lr] = f2bf(o_acc[mt][dt][r] * linv[r]);
            }
        }
    }
}

// ---------------- launch ----------------
extern "C" void kernel_launch(void* const* d_in, const int* in_sizes, int n_in,
                              void* d_out, int out_size, void* d_ws, size_t ws_size,
                              hipStream_t stream) {
    const float* x    = (const float*)d_in[0];
    const float* ln1g = (const float*)d_in[1];
    const float* ln1b = (const float*)d_in[2];
    const float* ln2g = (const float*)d_in[3];
    const float* ln2b = (const float*)d_in[4];
    const float* ln3g = (const float*)d_in[5];
    const float* ln3b = (const float*)d_in[6];
    const float* wq = (const float*)d_in[7];  const float* bq = (const float*)d_in[8];
    const float* wk = (const float*)d_in[9];  const float* bk = (const float*)d_in[10];
    const float* wv = (const float*)d_in[11]; const float* bv = (const float*)d_in[12];
    const float* wo = (const float*)d_in[13]; const float* bo = (const float*)d_in[14];
    const float* w1 = (const float*)d_in[15]; const float* b1 = (const float*)d_in[16];
    const float* w2 = (const float*)d_in[17]; const float* b2 = (const float*)d_in[18];
    const float* wd = (const float*)d_in[19]; const float* bd = (const float*)d_in[20];
    const float* wu = (const float*)d_in[21]; const float* bu = (const float*)d_in[22];
    float* out = (float*)d_out;

    char* base = (char*)d_ws;
    size_t off = 0;
    auto carve = [&](size_t bytes) -> char* {
        char* p = base + off; off += (bytes + 255) & ~(size_t)255; return p;
    };
    u16* qkv_wt = (u16*)carve(3072L * 1024 * 2);
    u16* wo_t   = (u16*)carve(1024L * 1024 * 2);
    u16* w1_t   = (u16*)carve(4096L * 1024 * 2);
    u16* w2_t   = (u16*)carve(1024L * 4096 * 2);
    u16* wd_t   = (u16*)carve(64L * 1024 * 2);
    u16* wu_t   = (u16*)carve(1024L * 64 * 2);
    float* bqkv = (float*)carve(3072L * 4);
    u16* hbuf   = (u16*)carve(4096L * 1024 * 2);
    u16* nrm    = (u16*)carve(4096L * 1024 * 2);
    u16* qkvb   = (u16*)carve(4096L * 3072 * 2);
    u16* vT     = (u16*)carve(64L * 64 * 1024 * 2);
    u16* ybuf   = (u16*)carve(4096L * 1024 * 2);
    float* hid  = (float*)carve(4096L * 1024 * 4);
    u16* mbuf   = (u16*)carve(4096L * 1024 * 2);
    u16* act    = (u16*)carve(4096L * 4096 * 2);
    u16* t1     = (u16*)carve(4096L * 64 * 2);
    u16* part   = (u16*)carve(4L * 4096 * 1024 * 2);  // split-K bf16 partials

    // prep: 8 weight transposes + qkv bias concat + LN1/LN3
    PrepParams pp;
    pp.src[0] = wq; pp.dst[0] = qkv_wt;                 pp.K[0] = 1024; pp.N[0] = 1024;
    pp.src[1] = wk; pp.dst[1] = qkv_wt + 1024L * 1024;  pp.K[1] = 1024; pp.N[1] = 1024;
    pp.src[2] = wv; pp.dst[2] = qkv_wt + 2048L * 1024;  pp.K[2] = 1024; pp.N[2] = 1024;
    pp.src[3] = wo; pp.dst[3] = wo_t;                   pp.K[3] = 1024; pp.N[3] = 1024;
    pp.src[4] = w1; pp.dst[4] = w1_t;                   pp.K[4] = 1024; pp.N[4] = 4096;
    pp.src[5] = w2; pp.dst[5] = w2_t;                   pp.K[5] = 4096; pp.N[5] = 1024;
    pp.src[6] = wd; pp.dst[6] = wd_t;                   pp.K[6] = 1024; pp.N[6] = 64;
    pp.src[7] = wu; pp.dst[7] = wu_t;                   pp.K[7] = 64;   pp.N[7] = 1024;
    int acc_blocks = 0;
    for (int j = 0; j < 8; ++j) {
        pp.pfx[j] = acc_blocks;
        acc_blocks += (pp.N[j] >> 6) * (pp.K[j] >> 6);
    }
    pp.pfx[8] = acc_blocks;
    pp.bq = bq; pp.bk = bk; pp.bv = bv; pp.bqkv = bqkv;
    pp.x = x; pp.g1 = ln1g; pp.b1 = ln1b; pp.g3 = ln3g; pp.b3 = ln3b;
    pp.o1 = hbuf; pp.o3 = nrm;
    prep_kernel<<<acc_blocks + 12 + 4096, 256, 0, stream>>>(pp);

    gemm_big<<<dim3(24, 32), 128, 0, stream>>>(hbuf, qkv_wt, 3072, 1024, 1024,
                                               EpiBF16Bias{qkvb, bqkv, 3072});
    transpose_v<<<dim3(32, 2, 64), dim3(32, 8), 0, stream>>>(qkvb, vT);
    attn_kernel<<<dim3(64, 8), 256, 0, stream>>>(qkvb, vT, ybuf);
    gemm_64<<<dim3(16, 32), 256, 0, stream>>>(ybuf, wo_t, 1024, 1024, 1024,
                                              EpiResid{hid, bo, x});
    ln_single_kernel<<<4096, 256, 0, stream>>>(hid, ln2g, ln2b, mbuf);
    gemm_big<<<dim3(32, 32), 128, 0, stream>>>(mbuf, w1_t, 4096, 1024, 1024,
                                               EpiGelu{act, b1});
    gemm_64<<<dim3(1, 32), 256, 0, stream>>>(nrm, wd_t, 64, 1024, 1024,
                                             EpiReluBF16{t1, bd});
    gemm_64<<<dim3(16, 32), 256, 0, stream>>>(t1, wu_t, 1024, 64, 64,
                                              EpiAdapter{out, bu, hid});
    // MLP2: split-K x4 into bf16 partials, then reduce
    gemm_big<<<dim3(8, 32, 4), 128, 0, stream>>>(act, w2_t, 1024, 1024, 4096,
                                                 EpiStoreSplit{part});
    reduce_out4<<<4096, 256, 0, stream>>>(out, part, b2);
}